// Round 1
// baseline (18168.379 us; speedup 1.0000x reference)
//
#include <hip/hip_runtime.h>

#define S 1024
#define NOBS 4096
#define TSTEPS 8192
#define NWG 512  // one wave per block; block g owns output columns 2g, 2g+1

#define AGENT __HIP_MEMORY_SCOPE_AGENT

typedef _Float16 half2v __attribute__((ext_vector_type(2)));
typedef _Float16 half4v __attribute__((ext_vector_type(4)));

#if __has_builtin(__builtin_amdgcn_fdot2)
#define FDOT2(a, b, c) __builtin_amdgcn_fdot2((a), (b), (c), false)
#else
#define FDOT2(a, b, c) ((c) + (float)(a)[0] * (float)(b)[0] + (float)(a)[1] * (float)(b)[1])
#endif

// ---------- DPP wave64 reductions (result valid in lane 63 only) ----------
template <int CTRL>
__device__ __forceinline__ float dpp_add(float x) {
  int s = __builtin_amdgcn_update_dpp(0, __builtin_bit_cast(int, x), CTRL, 0xf, 0xf, true);
  return x + __builtin_bit_cast(float, s);
}
template <int CTRL>
__device__ __forceinline__ float dpp_max(float x) {  // x >= 0 (zero-fill safe)
  int s = __builtin_amdgcn_update_dpp(0, __builtin_bit_cast(int, x), CTRL, 0xf, 0xf, true);
  return fmaxf(x, __builtin_bit_cast(float, s));
}
__device__ __forceinline__ float wave_sum63(float x) {
  x = dpp_add<0x111>(x);  // row_shr:1
  x = dpp_add<0x112>(x);  // row_shr:2
  x = dpp_add<0x114>(x);  // row_shr:4
  x = dpp_add<0x118>(x);  // row_shr:8  -> lane15 of each row16 has row sum
  x = dpp_add<0x142>(x);  // row_bcast15
  x = dpp_add<0x143>(x);  // row_bcast31 -> lane63 has full sum
  return x;
}
__device__ __forceinline__ float wave_max63(float x) {
  x = dpp_max<0x111>(x);
  x = dpp_max<0x112>(x);
  x = dpp_max<0x114>(x);
  x = dpp_max<0x118>(x);
  x = dpp_max<0x142>(x);
  x = dpp_max<0x143>(x);
  return x;
}

// ---------- one-time prep ----------
// Et[col][src] = exp(trans[src][col])  (transposed, fp16)
__global__ void prep_E(const float* __restrict__ trans, _Float16* __restrict__ Et) {
  __shared__ float tile[32][33];
  const int tx = threadIdx.x, ty = threadIdx.y;
  const int bi = blockIdx.y, bj = blockIdx.x;
  tile[ty][tx] = trans[(size_t)(bi * 32 + ty) * S + bj * 32 + tx];
  __syncthreads();
  Et[(size_t)(bj * 32 + ty) * S + bi * 32 + tx] = (_Float16)__expf(tile[tx][ty]);
}

// Bexp[obs][state] = exp(emit[state][obs])  (transposed, fp16)
__global__ void prep_B(const float* __restrict__ emit, _Float16* __restrict__ Bexp) {
  __shared__ float tile[32][33];
  const int tx = threadIdx.x, ty = threadIdx.y;
  const int bo = blockIdx.x;  // obs tile   (128)
  const int bs = blockIdx.y;  // state tile (32)
  tile[ty][tx] = emit[(size_t)(bs * 32 + ty) * NOBS + bo * 32 + tx];
  __syncthreads();
  Bexp[(size_t)(bo * 32 + ty) * S + bs * 32 + tx] = (_Float16)__expf(tile[tx][ty]);
}

// y_0[j] = exp(start[j]), published as {tag=0 : half2} per u64 (2 states/u64).
__global__ void hmm_init(const float* __restrict__ start, unsigned long long* rbuf) {
  const int tid = threadIdx.x;  // 512 threads
  half2v h = {(_Float16)__expf(start[2 * tid]), (_Float16)__expf(start[2 * tid + 1])};
  __hip_atomic_store(&rbuf[tid], (unsigned long long)__builtin_bit_cast(unsigned, h),
                     __ATOMIC_RELAXED, AGENT);  // tag 0 in hi32
}

// Poll the 8 u64 words this lane needs (states 4*lane + 256k + 0..3, k=0..3).
__device__ __forceinline__ void poll8(const unsigned long long* src, int lane, unsigned tag,
                                      unsigned long long (&w)[8]) {
  unsigned pend = 0xFFu;
  do {
#pragma unroll
    for (int j = 0; j < 8; ++j)
      if (pend & (1u << j))
        w[j] = __hip_atomic_load(src + (j >> 1) * 128 + 2 * lane + (j & 1), __ATOMIC_RELAXED,
                                 AGENT);
    unsigned np = 0;
#pragma unroll
    for (int j = 0; j < 8; ++j)
      if ((unsigned)(w[j] >> 32) != tag) np |= (1u << j);
    pend = np;
  } while (pend);
}

__global__ __launch_bounds__(64) void hmm_main(const int* __restrict__ obs,
                                               const _Float16* __restrict__ Et,
                                               const _Float16* __restrict__ Bexp,
                                               unsigned long long* rbuf,
                                               float* __restrict__ out) {
  const int lane = threadIdx.x;
  const int gid = blockIdx.x;  // owns columns 2*gid, 2*gid+1

  // E^T fragments for this wave's 2 columns (fp16 pairs, matches poll layout)
  half2v e0[8], e1[8];
#pragma unroll
  for (int k = 0; k < 4; ++k) {
    half4v a = *(const half4v*)(Et + (size_t)(2 * gid) * S + k * 256 + lane * 4);
    half4v b = *(const half4v*)(Et + (size_t)(2 * gid + 1) * S + k * 256 + lane * 4);
    e0[2 * k] = half2v{a[0], a[1]};
    e0[2 * k + 1] = half2v{a[2], a[3]};
    e1[2 * k] = half2v{b[0], b[1]};
    e1[2 * k + 1] = half2v{b[2], b[3]};
  }

  // b_0 = exp(emit[:, obs[0]]) for this lane's 16 source states
  half2v bh[8], bhn[8];
  {
    const int o0 = obs[0];
#pragma unroll
    for (int k = 0; k < 4; ++k) {
      half4v v = *(const half4v*)(Bexp + (size_t)o0 * S + k * 256 + lane * 4);
      bh[2 * k] = half2v{v[0], v[1]};
      bh[2 * k + 1] = half2v{v[2], v[3]};
    }
  }
  int obs_nx = obs[1];

  _Float16 hinv = (_Float16)1.0f;  // inv_1 = 1
  float linv = 0.0f;               // log of the inv consumed this step
  double c = 0.0;                  // running log-scale D_t (identical in every wave)
  unsigned long long w[8];

  for (int t = 1; t < TSTEPS; ++t) {
    // prefetch b_t = Bexp[obs[t]] (used next step) and obs[t+1] — off critical path
    const int on = obs_nx;
#pragma unroll
    for (int k = 0; k < 4; ++k) {
      half4v v = *(const half4v*)(Bexp + (size_t)on * S + k * 256 + lane * 4);
      bhn[2 * k] = half2v{v[0], v[1]};
      bhn[2 * k + 1] = half2v{v[2], v[3]};
    }
    obs_nx = obs[(t + 1 < TSTEPS) ? (t + 1) : (TSTEPS - 1)];

    // wait for the full y_{t-1} vector (this lane's 16 states)
    const unsigned long long* src = rbuf + ((t & 1) ? 0 : 512);
    poll8(src, lane, (unsigned)(t - 1), w);

    // p = (y * b_{t-1}) * inv_t   (two pk_muls; staged order keeps fp16 normal-range)
    const half2v hinv2 = {hinv, hinv};
    half2v p[8];
#pragma unroll
    for (int j = 0; j < 8; ++j)
      p[j] = (__builtin_bit_cast(half2v, (unsigned)w[j]) * bh[j]) * hinv2;

    // dot with E^T fragments, two columns
    float a0 = 0.f, a1 = 0.f;
#pragma unroll
    for (int j = 0; j < 8; ++j) {
      a0 = FDOT2(p[j], e0[j], a0);
      a1 = FDOT2(p[j], e1[j], a1);
    }
    a0 = wave_sum63(a0);
    a1 = wave_sum63(a1);
    if (lane == 63) {
      half2v hr = {(_Float16)a0, (_Float16)a1};  // RNE — unbiased
      const unsigned long long msg = ((unsigned long long)(unsigned)t << 32) |
                                     (unsigned long long)__builtin_bit_cast(unsigned, hr);
      __hip_atomic_store(rbuf + ((t & 1) ? 512 : 0) + gid, msg, __ATOMIC_RELAXED, AGENT);
    }

    // ---- off the critical path: scale bookkeeping for the next step ----
    c -= (double)linv;
    float mp = 0.f;
#pragma unroll
    for (int j = 0; j < 8; ++j)
      mp = fmaxf(mp, fmaxf((float)p[j][0], (float)p[j][1]));
    mp = wave_max63(mp);
    const float M =
        __builtin_bit_cast(float, __builtin_amdgcn_readlane(__builtin_bit_cast(int, mp), 63));
    const float inv = fminf(1.0f / (256.0f * M), 60000.0f);
    hinv = (_Float16)inv;
    linv = __logf((float)hinv);  // log of the *actually applied* (fp16-rounded) scale
#pragma unroll
    for (int j = 0; j < 8; ++j) bh[j] = bhn[j];
  }

  // Final: ans = D_{T-1} + log( sum_j y_{T-1}[j] * b_{T-1}[j] ), block 0 only.
  if (gid == 0) {
    poll8(rbuf + 512, lane, (unsigned)(TSTEPS - 1), w);  // parity of 8191 = 1
    float s = 0.f;
#pragma unroll
    for (int j = 0; j < 8; ++j)
      s = FDOT2(__builtin_bit_cast(half2v, (unsigned)w[j]), bh[j], s);
    s = wave_sum63(s);
    if (lane == 63) out[0] = (float)(c + (double)__logf(s));
  }
}

extern "C" void kernel_launch(void* const* d_in, const int* in_sizes, int n_in, void* d_out,
                              int out_size, void* d_ws, size_t ws_size, hipStream_t stream) {
  const int* obs = (const int*)d_in[0];
  const float* start = (const float*)d_in[1];
  const float* trans = (const float*)d_in[2];
  const float* emit = (const float*)d_in[3];

  // ws layout: 0: rbuf[2][512] u64 (8 KB) | 16384: Et 1024*1024 fp16 (2 MB)
  //            | 16384+2MB: Bexp 4096*1024 fp16 (8 MB)
  unsigned long long* rbuf = (unsigned long long*)d_ws;
  _Float16* Et = (_Float16*)((char*)d_ws + 16384);
  _Float16* Bexp = (_Float16*)((char*)d_ws + 16384 + (size_t)S * S * sizeof(_Float16));

  prep_E<<<dim3(32, 32), dim3(32, 32), 0, stream>>>(trans, Et);
  prep_B<<<dim3(128, 32), dim3(32, 32), 0, stream>>>(emit, Bexp);
  hmm_init<<<1, 512, 0, stream>>>(start, rbuf);
  hmm_main<<<NWG, 64, 0, stream>>>(obs, Et, Bexp, rbuf, (float*)d_out);
}

// Round 3
// 12542.470 us; speedup vs baseline: 1.4485x; 1.4485x over previous
//
#include <hip/hip_runtime.h>

#define S 1024
#define NOBS 4096
#define TSTEPS 8192
#define NWG 64
#define NTHR 512  // 8 waves; thread t owns states 2t, 2t+1
#define NWAVE 8

#define AGENT __HIP_MEMORY_SCOPE_AGENT

typedef _Float16 half2v __attribute__((ext_vector_type(2)));
typedef _Float16 half4v __attribute__((ext_vector_type(4)));
typedef unsigned long long u64;

#if __has_builtin(__builtin_amdgcn_fdot2)
#define FDOT2(a, b, c) __builtin_amdgcn_fdot2((a), (b), (c), false)
#else
#define FDOT2(a, b, c) ((c) + (float)(a)[0] * (float)(b)[0] + (float)(a)[1] * (float)(b)[1])
#endif

// ---------- DPP wave64 reductions (result valid in lane 63) ----------
template <int CTRL>
__device__ __forceinline__ float dpp_add(float x) {
  int s = __builtin_amdgcn_update_dpp(0, __builtin_bit_cast(int, x), CTRL, 0xf, 0xf, true);
  return x + __builtin_bit_cast(float, s);
}
template <int CTRL>
__device__ __forceinline__ float dpp_max(float x) {  // x >= 0 (zero-fill safe)
  int s = __builtin_amdgcn_update_dpp(0, __builtin_bit_cast(int, x), CTRL, 0xf, 0xf, true);
  return fmaxf(x, __builtin_bit_cast(float, s));
}
__device__ __forceinline__ float wave_sum63(float x) {
  x = dpp_add<0x111>(x);  // row_shr:1
  x = dpp_add<0x112>(x);  // row_shr:2
  x = dpp_add<0x114>(x);  // row_shr:4
  x = dpp_add<0x118>(x);  // row_shr:8
  x = dpp_add<0x142>(x);  // row_bcast:15
  x = dpp_add<0x143>(x);  // row_bcast:31
  return x;
}
__device__ __forceinline__ float wave_max63(float x) {
  x = dpp_max<0x111>(x);
  x = dpp_max<0x112>(x);
  x = dpp_max<0x114>(x);
  x = dpp_max<0x118>(x);
  x = dpp_max<0x142>(x);
  x = dpp_max<0x143>(x);
  return x;
}

// ---------- one-time prep ----------
// Et[col][src] = exp(trans[src][col])  (transposed, fp16)
__global__ void prep_E(const float* __restrict__ trans, _Float16* __restrict__ Et) {
  __shared__ float tile[32][33];
  const int tx = threadIdx.x, ty = threadIdx.y;
  const int bi = blockIdx.y, bj = blockIdx.x;
  tile[ty][tx] = trans[(size_t)(bi * 32 + ty) * S + bj * 32 + tx];
  __syncthreads();
  Et[(size_t)(bj * 32 + ty) * S + bi * 32 + tx] = (_Float16)__expf(tile[tx][ty]);
}

// Bexp[obs][state] = exp(emit[state][obs])  (transposed, fp16)
__global__ void prep_B(const float* __restrict__ emit, _Float16* __restrict__ Bexp) {
  __shared__ float tile[32][33];
  const int tx = threadIdx.x, ty = threadIdx.y;
  const int bo = blockIdx.x;  // obs tile   (128)
  const int bs = blockIdx.y;  // state tile (32)
  tile[ty][tx] = emit[(size_t)(bs * 32 + ty) * NOBS + bo * 32 + tx];
  __syncthreads();
  Bexp[(size_t)(bo * 32 + ty) * S + bs * 32 + tx] = (_Float16)__expf(tile[tx][ty]);
}

// z_0[j] = exp(start[j] + emit[j][obs0]), packed {tag=0|fp16} per u32, u64 per thread.
__global__ void hmm_init(const int* __restrict__ obs, const float* __restrict__ start,
                         const float* __restrict__ emit, u64* rbuf) {
  const int tid = threadIdx.x;  // 512 threads
  const int o0 = obs[0];
  const float z0 = __expf(start[2 * tid] + emit[(size_t)(2 * tid) * NOBS + o0]);
  const float z1 = __expf(start[2 * tid + 1] + emit[(size_t)(2 * tid + 1) * NOBS + o0]);
  const unsigned lo = (unsigned)__builtin_bit_cast(unsigned short, (_Float16)z0);
  const unsigned hi = (unsigned)__builtin_bit_cast(unsigned short, (_Float16)z1);
  __hip_atomic_store(&rbuf[tid], ((u64)hi << 32) | (u64)lo, __ATOMIC_RELAXED, AGENT);
}

// 4-deep pipelined poll of one u64: detection quantum ~ load_latency/4.
__device__ __forceinline__ u64 poll1(const u64* a, unsigned tag) {
  const u64 pat = ((u64)tag << 16) | ((u64)tag << 48);
  const u64 msk = 0xFFFF0000FFFF0000ULL;
  u64 w0 = __hip_atomic_load(a, __ATOMIC_RELAXED, AGENT);
  u64 w1 = __hip_atomic_load(a, __ATOMIC_RELAXED, AGENT);
  u64 w2 = __hip_atomic_load(a, __ATOMIC_RELAXED, AGENT);
  u64 w3 = __hip_atomic_load(a, __ATOMIC_RELAXED, AGENT);
  for (;;) {
    if ((w0 & msk) == pat) return w0;
    w0 = __hip_atomic_load(a, __ATOMIC_RELAXED, AGENT);
    if ((w1 & msk) == pat) return w1;
    w1 = __hip_atomic_load(a, __ATOMIC_RELAXED, AGENT);
    if ((w2 & msk) == pat) return w2;
    w2 = __hip_atomic_load(a, __ATOMIC_RELAXED, AGENT);
    if ((w3 & msk) == pat) return w3;
    w3 = __hip_atomic_load(a, __ATOMIC_RELAXED, AGENT);
  }
}

// Final-read poll of 8 u64 (one wave covers all 512 words).
__device__ __forceinline__ void poll8f(const u64* s64, unsigned tag, u64 (&w)[8]) {
  const u64 pat = ((u64)tag << 16) | ((u64)tag << 48);
  const u64 msk = 0xFFFF0000FFFF0000ULL;
  unsigned pend = 0xFFu;
  do {
#pragma unroll
    for (int j = 0; j < 8; ++j)
      if (pend & (1u << j)) w[j] = __hip_atomic_load(&s64[j], __ATOMIC_RELAXED, AGENT);
    unsigned np = 0;
#pragma unroll
    for (int j = 0; j < 8; ++j)
      if ((w[j] & msk) != pat) np |= 1u << j;
    pend = np;
  } while (pend);
}

__device__ __forceinline__ half2v h2max(half2v a, half2v b) {
  return half2v{a[0] > b[0] ? a[0] : b[0], a[1] > b[1] ? a[1] : b[1]};
}

__global__ __launch_bounds__(NTHR) void hmm_main(const int* __restrict__ obs,
                                                 const _Float16* __restrict__ Et,
                                                 const unsigned* __restrict__ Bexp32,
                                                 u64* rbuf, float* __restrict__ out) {
  __shared__ __align__(16) unsigned pbuf[2][S / 2];  // fp16 pairs, 4 KB total
  const int tid = threadIdx.x;
  const int lane = tid & 63;
  const int wave = tid >> 6;
  const int wg = blockIdx.x;
  // XCD swizzle: each XCD's 8 WGs own contiguous column chunks.
  const int chunk = (wg & 7) * 8 + (wg >> 3);
  const int c0 = chunk * 16 + wave * 2;  // this wave's two output columns

  // E^T fragments: e[2k],e[2k+1] cover sources {k*256 + 4*lane .. +3} (fp16 pairs).
  half2v e0[8], e1[8];
#pragma unroll
  for (int k = 0; k < 4; ++k) {
    const half4v a = *(const half4v*)(Et + (size_t)c0 * S + k * 256 + lane * 4);
    const half4v b = *(const half4v*)(Et + (size_t)(c0 + 1) * S + k * 256 + lane * 4);
    e0[2 * k] = half2v{a[0], a[1]};
    e0[2 * k + 1] = half2v{a[2], a[3]};
    e1[2 * k] = half2v{b[0], b[1]};
    e1[2 * k + 1] = half2v{b[2], b[3]};
  }

  u64* const b0 = rbuf;          // even-t buffer (init writes here as t=0)
  u64* const b1 = rbuf + S / 2;  // odd-t buffer

  _Float16 hinv = (_Float16)1.0f;  // scale applied to incoming z this step
  double c = 0.0;                  // -sum(log applied scales); identical in all waves
  int ob = obs[1];

  for (int t = 1; t < TSTEPS; ++t) {
    // this wave's two emission scalars for step t (fp16 pair, one u32) — issued
    // before the poll so its latency hides under the wait
    const unsigned b2u = Bexp32[(size_t)ob * (S / 2) + (c0 >> 1)];
    ob = obs[(t + 1 < TSTEPS) ? (t + 1) : (TSTEPS - 1)];

    // wait for the u64 this thread owns (states 2*tid, 2*tid+1 of z_{t-1})
    const u64* src = ((t & 1) ? b0 : b1) + tid;
    const u64 w = poll1(src, (unsigned)(t - 1));

    // p = z * hinv  (one byte-perm + one pk_mul), publish to LDS
    const unsigned zz = __builtin_amdgcn_perm((unsigned)(w >> 32), (unsigned)w, 0x05040100);
    const half2v p2 = __builtin_bit_cast(half2v, zz) * half2v{hinv, hinv};
    pbuf[t & 1][tid] = __builtin_bit_cast(unsigned, p2);
    __syncthreads();  // the only barrier per step

    // dot over all 1024 p values for two columns (fp16 dot2, fp32 accum)
    const unsigned* pb = pbuf[t & 1];
    half2v pp[8];
    float a0 = 0.f, a1 = 0.f;
#pragma unroll
    for (int k = 0; k < 4; ++k) {
      const u64 pr = *reinterpret_cast<const u64*>(pb + k * 128 + 2 * lane);
      pp[2 * k] = __builtin_bit_cast(half2v, (unsigned)pr);
      pp[2 * k + 1] = __builtin_bit_cast(half2v, (unsigned)(pr >> 32));
    }
#pragma unroll
    for (int j = 0; j < 8; ++j) {
      a0 = FDOT2(pp[j], e0[j], a0);
      a1 = FDOT2(pp[j], e1[j], a1);
    }
    a0 = wave_sum63(a0);
    a1 = wave_sum63(a1);

    // publish z_t = y_t * b_t for both columns as one tagged u64
    if (lane == 63) {
      const half2v zh = half2v{(_Float16)a0, (_Float16)a1} * __builtin_bit_cast(half2v, b2u);
      const unsigned z10 = __builtin_bit_cast(unsigned, zh);
      const unsigned tg = (unsigned)t << 16;
      const u64 msg = ((u64)(tg | (z10 >> 16)) << 32) | (u64)(tg | (z10 & 0xFFFFu));
      __hip_atomic_store(((t & 1) ? b1 : b0) + (c0 >> 1), msg, __ATOMIC_RELAXED, AGENT);
    }

    // ---- off the critical path: next step's scale (skip on last step) ----
    // ABSOLUTE rescale (validated in R1): y_t <= 1024*max(p_t), b<=1 =>
    // p_{t+1} = z_t/(256*max(p_t)) <= 4, published z <= 4096 < fp16 max.
    // (The R2 incremental form hinv/mp = 1/max(z_{t-1}) is stale-by-one and
    //  oscillates -> fp16 overflow -> NaN. Do not reintroduce.)
    if (t != TSTEPS - 1) {
      half2v m2 = pp[0];
#pragma unroll
      for (int j = 1; j < 8; ++j) m2 = h2max(m2, pp[j]);
      float mp = fmaxf((float)m2[0], (float)m2[1]);
      mp = wave_max63(mp);  // lanes jointly cover all 1024 states
      mp = __builtin_bit_cast(float,
                              __builtin_amdgcn_readlane(__builtin_bit_cast(int, mp), 63));
      const float nxt = fminf(1.0f / (256.0f * mp), 60000.0f);
      hinv = (_Float16)nxt;
      c -= (double)__logf((float)hinv);  // log of the *applied* (fp16-rounded) scale
    }
  }

  // Final: out = c + log( sum_j z_{T-1}[j] ), WG 0 wave 0 (t=8191 is odd -> b1).
  if (wg == 0 && wave == 0) {
    u64 w[8];
    poll8f(b1 + lane * 8, (unsigned)(TSTEPS - 1), w);
    float s = 0.f;
#pragma unroll
    for (int j = 0; j < 8; ++j) {
      const unsigned zz =
          __builtin_amdgcn_perm((unsigned)(w[j] >> 32), (unsigned)w[j], 0x05040100);
      const half2v z2 = __builtin_bit_cast(half2v, zz);
      s += (float)z2[0] + (float)z2[1];
    }
    s = wave_sum63(s);
    if (lane == 63) out[0] = (float)(c + (double)__logf(s));
  }
}

extern "C" void kernel_launch(void* const* d_in, const int* in_sizes, int n_in, void* d_out,
                              int out_size, void* d_ws, size_t ws_size, hipStream_t stream) {
  const int* obs = (const int*)d_in[0];
  const float* start = (const float*)d_in[1];
  const float* trans = (const float*)d_in[2];
  const float* emit = (const float*)d_in[3];

  // ws layout: 0: rbuf[2][512] u64 (8 KB) | 16384: Et 1024*1024 fp16 (2 MB)
  //            | +2MB: Bexp 4096*1024 fp16 (8 MB)
  u64* rbuf = (u64*)d_ws;
  _Float16* Et = (_Float16*)((char*)d_ws + 16384);
  _Float16* Bexp = (_Float16*)((char*)d_ws + 16384 + (size_t)S * S * sizeof(_Float16));

  prep_E<<<dim3(32, 32), dim3(32, 32), 0, stream>>>(trans, Et);
  prep_B<<<dim3(128, 32), dim3(32, 32), 0, stream>>>(emit, Bexp);
  hmm_init<<<1, NTHR, 0, stream>>>(obs, start, emit, rbuf);
  hmm_main<<<NWG, NTHR, 0, stream>>>(obs, Et, (const unsigned*)Bexp, rbuf, (float*)d_out);
}